// Round 8
// baseline (56.160 us; speedup 1.0000x reference)
//
#include <hip/hip_runtime.h>
#include <hip/hip_bf16.h>

#define CIN   128
#define HH    64
#define WW    64
#define COUT  256
#define HO    64
#define WO    64
#define NTAP  9
#define KTOT  (CIN*NTAP)   /* 1152 */
#define BK    32
#define NSTEP (KTOT/BK)    /* 36 */
#define NB    8
#define CROW  272          /* cols row stride in bytes (256 data + 16 pad) */
#define CBUF  (WO*CROW)    /* one cols buffer: 17408 B */

typedef __attribute__((ext_vector_type(8))) short bf16x8;
typedef __attribute__((ext_vector_type(4))) short bf16x4;
typedef __attribute__((ext_vector_type(4))) float f32x4;

struct __align__(16) TapEntry {
  int   i00, i01, i10, i11;    // BYTE offsets into xt's per-image slice
  float w00, w01, w10, w11;
};

static __device__ __forceinline__ ushort f2bf(float v) {
  unsigned u = __float_as_uint(v);
  unsigned rnd = 0x7fffu + ((u >> 16) & 1u);
  return (ushort)((u + rnd) >> 16);
}
static __device__ __forceinline__ float bf2f(short s) {
  return __uint_as_float(((unsigned)(unsigned short)s) << 16);
}

// ---- prep: x NCHW f32 -> xt NHWC bf16  +  weight repack to wbt ----
// wbt element (s, c16, lane=q*16+r, j) = w[co=c16*16+r][ci=(s&3)*32+q*8+j][tap=s>>2]
__global__ __launch_bounds__(256) void prep(const float* __restrict__ x,
                                            const float* __restrict__ w,
                                            ushort* __restrict__ xt,
                                            ushort* __restrict__ wbt) {
  const int blk = blockIdx.x;
  const int tid = threadIdx.x;
  if (blk < NB * HH) {
    const int b = blk >> 6, y = blk & 63;
    const int px = tid & 63, c8 = tid >> 6;
    const float* src = x + (size_t)b * CIN * HH * WW + y * WW + px;
    ushort* dst = xt + (((size_t)(b * HH + y) * WW) + px) * CIN;
    #pragma unroll
    for (int cc = 0; cc < 4; ++cc) {
      const int c0 = cc * 32 + c8 * 8;
      bf16x8 v;
      #pragma unroll
      for (int j = 0; j < 8; ++j)
        v[j] = (short)f2bf(src[(size_t)(c0 + j) * (HH * WW)]);
      *reinterpret_cast<bf16x8*>(dst + c0) = v;
    }
  } else {
    const int h = (blk - NB * HH) * 256 + tid;
    const int s   = h >> 10;
    const int c16 = (h >> 6) & 15;
    const int l   = h & 63;
    const int q   = l >> 4;
    const int r   = l & 15;
    const int co  = c16 * 16 + r;
    const int tap = s >> 2;
    const int ci0 = (s & 3) * 32 + q * 8;
    bf16x8 o;
    #pragma unroll
    for (int j = 0; j < 8; ++j)
      o[j] = (short)f2bf(w[(size_t)(co * CIN + ci0 + j) * NTAP + tap]);
    *reinterpret_cast<bf16x8*>(wbt + (size_t)h * 8) = o;
  }
}

// ---- main: 8-wave block, within-block K-split (taps 0-4 | 5-8) ----
__global__ __launch_bounds__(512, 4)
void dcn7(const ushort* __restrict__ xt, const float* __restrict__ off,
          const ushort* __restrict__ wbt, float* __restrict__ out)
{
  __shared__ TapEntry taps[NTAP * WO];                 // 18432 B
  __shared__ __align__(16) char colsB[2 * CBUF];       // 2 groups x 17408 B

  const int tid = threadIdx.x;
  // b in low 3 bits: all 64 blocks of one image land on one XCD (L2 locality)
  const int b  = blockIdx.x & 7;
  const int ho = blockIdx.x >> 3;

  for (int e = tid; e < NTAP * WO; e += 512) {
    const int k  = e >> 6;
    const int wo = e & 63;
    const float* op = off + (((size_t)(b * 18 + 2 * k) * HO + ho) * WO + wo);
    const float dy = op[0];
    const float dx = op[HO * WO];
    const float py  = (float)(ho - 1 + (k / 3)) + dy;
    const float pxf = (float)(wo - 1 + (k % 3)) + dx;
    const float y0f = floorf(py), x0f = floorf(pxf);
    const float fy = py - y0f, fx = pxf - x0f;
    const int y0 = (int)y0f, x0 = (int)x0f;
    const int y1 = y0 + 1,  x1 = x0 + 1;
    const bool vy0 = (unsigned)y0 < HH, vy1 = (unsigned)y1 < HH;
    const bool vx0 = (unsigned)x0 < WW, vx1 = (unsigned)x1 < WW;
    const int cy0 = min(max(y0, 0), HH - 1), cy1 = min(max(y1, 0), HH - 1);
    const int cx0 = min(max(x0, 0), WW - 1), cx1 = min(max(x1, 0), WW - 1);
    TapEntry t;
    t.i00 = (cy0 * WW + cx0) << 8;  t.i01 = (cy0 * WW + cx1) << 8;  // *CIN*2B
    t.i10 = (cy1 * WW + cx0) << 8;  t.i11 = (cy1 * WW + cx1) << 8;
    const float gy = 1.f - fy, gx = 1.f - fx;
    t.w00 = (vy0 && vx0) ? gy * gx : 0.f;
    t.w01 = (vy0 && vx1) ? gy * fx : 0.f;
    t.w10 = (vy1 && vx0) ? fy * gx : 0.f;
    t.w11 = (vy1 && vx1) ? fy * fx : 0.f;
    taps[e] = t;
  }

  const int w     = tid >> 6;     // wave 0..7
  const int group = w >> 2;       // 0: taps 0-4, 1: taps 5-8
  const int grp   = w & 3;        // co-group / px-group within the group
  const int lane  = tid & 63;
  const int l15   = lane & 15;
  const int q     = lane >> 4;
  const int g     = q;            // gather: pixel-subindex within quad
  const int s16b  = l15 * 16;     // gather: byte offset of 16B chunk in 256B row

  f32x4 acc[4][4];
  #pragma unroll
  for (int m = 0; m < 4; ++m)
    #pragma unroll
    for (int n = 0; n < 4; ++n)
      acc[m][n] = 0.f;

  const char* xb = reinterpret_cast<const char*>(xt)
                 + (size_t)b * (HH * WW * CIN * 2) + s16b;
  char* mycols = colsB + group * CBUF;

  __syncthreads();   // taps ready

  #pragma unroll 1
  for (int r = 0; r < 5; ++r) {
    const int  tap    = group ? (5 + r) : r;
    const bool active = group ? (r < 4) : true;

    __syncthreads();   // previous round's cols reads done (overwrite safe)

    if (active) {
      // gather: 4 pixels, 4 corners each; 16B/lane contiguous per 16-lane group
      #pragma unroll
      for (int pq = 0; pq < 4; ++pq) {
        const int px = (grp << 4) + (pq << 2) + g;
        const TapEntry te = taps[tap * WO + px];
        const bf16x8 c00 = *reinterpret_cast<const bf16x8*>(xb + te.i00);
        const bf16x8 c01 = *reinterpret_cast<const bf16x8*>(xb + te.i01);
        const bf16x8 c10 = *reinterpret_cast<const bf16x8*>(xb + te.i10);
        const bf16x8 c11 = *reinterpret_cast<const bf16x8*>(xb + te.i11);
        bf16x8 hv;
        #pragma unroll
        for (int j = 0; j < 8; ++j) {
          const float v = te.w00 * bf2f(c00[j]) + te.w01 * bf2f(c01[j])
                        + te.w10 * bf2f(c10[j]) + te.w11 * bf2f(c11[j]);
          hv[j] = (short)f2bf(v);
        }
        *reinterpret_cast<bf16x8*>(mycols + px * CROW + s16b) = hv;
      }
    }

    __syncthreads();   // cols ready

    if (active) {
      #pragma unroll
      for (int kk = 0; kk < 4; ++kk) {
        const int s = tap * 4 + kk;
        bf16x8 a[4], bb[4];
        #pragma unroll
        for (int m = 0; m < 4; ++m)
          a[m] = *reinterpret_cast<const bf16x8*>(
              wbt + ((size_t)((s * 16 + grp * 4 + m) * 64 + lane)) * 8);
        #pragma unroll
        for (int n = 0; n < 4; ++n)
          bb[n] = *reinterpret_cast<const bf16x8*>(
              mycols + (n * 16 + l15) * CROW + kk * 64 + q * 16);
        #pragma unroll
        for (int m = 0; m < 4; ++m)
          #pragma unroll
          for (int n = 0; n < 4; ++n)
            acc[m][n] = __builtin_amdgcn_mfma_f32_16x16x32_bf16(
                a[m], bb[n], acc[m][n], 0, 0, 0);
      }
    }
  }

  // ---- cross-group reduction through LDS (reuse colsB; conflict-free b128) ----
  f32x4* red = reinterpret_cast<f32x4*>(colsB);
  const int t256 = tid & 255;
  #pragma unroll
  for (int p = 0; p < 2; ++p) {
    __syncthreads();
    if (group == 1) {
      #pragma unroll
      for (int m2 = 0; m2 < 2; ++m2)
        #pragma unroll
        for (int n = 0; n < 4; ++n)
          red[(m2 * 4 + n) * 256 + t256] = acc[p * 2 + m2][n];
    }
    __syncthreads();
    if (group == 0) {
      #pragma unroll
      for (int m2 = 0; m2 < 2; ++m2)
        #pragma unroll
        for (int n = 0; n < 4; ++n) {
          const f32x4 v = red[(m2 * 4 + n) * 256 + t256];
          acc[p * 2 + m2][n] += v;
        }
    }
  }

  // ---- epilogue (group 0 only): D row(co)=q*4+rr (+m*16), col(wo)=l15 (+n*16) ----
  if (group == 0) {
    #pragma unroll
    for (int m = 0; m < 4; ++m)
      #pragma unroll
      for (int n = 0; n < 4; ++n)
        #pragma unroll
        for (int rr = 0; rr < 4; ++rr) {
          const int co = grp * 64 + m * 16 + q * 4 + rr;
          const int wo = n * 16 + l15;
          out[(((size_t)b * COUT + co) * HO + ho) * WO + wo] = acc[m][n][rr];
        }
  }
}

// ---- fallback (ws too small): round-1 f32-gather path ----
__global__ __launch_bounds__(256, 2)
void dcn_f32(const float* __restrict__ x, const float* __restrict__ off,
             const float* __restrict__ wgt, float* __restrict__ out)
{
  __shared__ TapEntry taps[NTAP * WO];
  __shared__ __align__(16) ushort colsf[WO * 40];
  const int tid = threadIdx.x;
  const int b  = blockIdx.x & 7;
  const int ho = blockIdx.x >> 3;
  for (int e = tid; e < NTAP * WO; e += 256) {
    const int k  = e >> 6;
    const int wo = e & 63;
    const float* op = off + (((size_t)(b * 18 + 2 * k) * HO + ho) * WO + wo);
    const float dy = op[0];
    const float dx = op[HO * WO];
    const float py  = (float)(ho - 1 + (k / 3)) + dy;
    const float pxf = (float)(wo - 1 + (k % 3)) + dx;
    const float y0f = floorf(py), x0f = floorf(pxf);
    const float fy = py - y0f, fx = pxf - x0f;
    const int y0 = (int)y0f, x0 = (int)x0f;
    const int y1 = y0 + 1,  x1 = x0 + 1;
    const bool vy0 = (unsigned)y0 < HH, vy1 = (unsigned)y1 < HH;
    const bool vx0 = (unsigned)x0 < WW, vx1 = (unsigned)x1 < WW;
    const int cy0 = min(max(y0, 0), HH - 1), cy1 = min(max(y1, 0), HH - 1);
    const int cx0 = min(max(x0, 0), WW - 1), cx1 = min(max(x1, 0), WW - 1);
    TapEntry t;
    t.i00 = cy0 * WW + cx0; t.i01 = cy0 * WW + cx1;
    t.i10 = cy1 * WW + cx0; t.i11 = cy1 * WW + cx1;
    const float gy = 1.f - fy, gx = 1.f - fx;
    t.w00 = (vy0 && vx0) ? gy * gx : 0.f;
    t.w01 = (vy0 && vx1) ? gy * fx : 0.f;
    t.w10 = (vy1 && vx0) ? fy * gx : 0.f;
    t.w11 = (vy1 && vx1) ? fy * fx : 0.f;
    taps[e] = t;
  }
  const int px = tid & 63, grp = tid >> 6, lane = tid & 63;
  const int l15 = lane & 15, q = lane >> 4;
  f32x4 acc[4][4];
  #pragma unroll
  for (int m = 0; m < 4; ++m)
    #pragma unroll
    for (int n = 0; n < 4; ++n) acc[m][n] = 0.f;
  const float* xb = x + (size_t)b * CIN * HH * WW;
  __syncthreads();
  for (int tap = 0; tap < NTAP; ++tap) {
    const TapEntry e = taps[tap * WO + px];
    for (int cb = 0; cb < 4; ++cb) {
      __syncthreads();
      {
        const float* xp = xb + (size_t)(cb * 32 + grp * 8) * (HH * WW);
        bf16x8 hv;
        #pragma unroll
        for (int j = 0; j < 8; ++j) {
          const float* p = xp + j * (HH * WW);
          const float v = e.w00 * p[e.i00] + e.w01 * p[e.i01]
                        + e.w10 * p[e.i10] + e.w11 * p[e.i11];
          hv[j] = (short)f2bf(v);
        }
        *reinterpret_cast<bf16x8*>(
            reinterpret_cast<char*>(colsf) + px * 80 + grp * 16) = hv;
      }
      __syncthreads();
      bf16x8 a[4], bbf[4];
      #pragma unroll
      for (int m = 0; m < 4; ++m) {
        const int co = grp * 64 + m * 16 + l15;
        bf16x8 t;
        #pragma unroll
        for (int j = 0; j < 8; ++j)
          t[j] = (short)f2bf(wgt[(size_t)(co * CIN + cb * 32 + q * 8 + j) * NTAP + tap]);
        a[m] = t;
      }
      #pragma unroll
      for (int n = 0; n < 4; ++n)
        bbf[n] = *reinterpret_cast<const bf16x8*>(
            reinterpret_cast<const char*>(colsf) + (n * 16 + l15) * 80 + q * 16);
      #pragma unroll
      for (int m = 0; m < 4; ++m)
        #pragma unroll
        for (int n = 0; n < 4; ++n)
          acc[m][n] = __builtin_amdgcn_mfma_f32_16x16x32_bf16(
              a[m], bbf[n], acc[m][n], 0, 0, 0);
    }
  }
  const int wco = grp * 64;
  #pragma unroll
  for (int m = 0; m < 4; ++m)
    #pragma unroll
    for (int n = 0; n < 4; ++n)
      #pragma unroll
      for (int r = 0; r < 4; ++r) {
        const int co = wco + m * 16 + q * 4 + r;
        const int wo = n * 16 + l15;
        out[(((size_t)b * COUT + co) * HO + ho) * WO + wo] = acc[m][n][r];
      }
}

extern "C" void kernel_launch(void* const* d_in, const int* in_sizes, int n_in,
                              void* d_out, int out_size, void* d_ws, size_t ws_size,
                              hipStream_t stream) {
  const float* x   = (const float*)d_in[0];   // [8,128,64,64]
  const float* off = (const float*)d_in[1];   // [8,18,64,64]
  const float* wgt = (const float*)d_in[2];   // [256,128,3,3]
  float* out = (float*)d_out;                 // [8,256,64,64]

  const size_t xt_bytes = (size_t)NB * HH * WW * CIN * sizeof(ushort);   // 8 MiB
  const size_t wb_bytes = (size_t)NSTEP * COUT * BK * sizeof(ushort);    // 576 KiB
  if (ws_size >= xt_bytes + wb_bytes) {
    ushort* xtp  = (ushort*)d_ws;
    ushort* wbtp = (ushort*)((char*)d_ws + xt_bytes);
    const int wchunks = NSTEP * COUT * BK / 8;        // 36864 16B chunks
    const int wblocks = wchunks / 256;                // 144
    prep<<<NB * HH + wblocks, 256, 0, stream>>>(x, wgt, xtp, wbtp);
    dcn7<<<NB * HO, 512, 0, stream>>>(xtp, off, wbtp, out);
  } else {
    dcn_f32<<<NB * HO, 256, 0, stream>>>(x, off, wgt, out);
  }
}

// Round 9
// 51.052 us; speedup vs baseline: 1.1001x; 1.1001x over previous
//
#include <hip/hip_runtime.h>
#include <hip/hip_bf16.h>

#define CIN   128
#define HH    64
#define WW    64
#define COUT  256
#define HO    64
#define WO    64
#define NTAP  9
#define KTOT  (CIN*NTAP)   /* 1152 */
#define BK    32
#define NSTEP (KTOT/BK)    /* 36 */
#define NB    8
#define PXB   32           /* pixels per block */
#define CROW  272          /* cols row stride in bytes (256 data + 16 pad) */

typedef __attribute__((ext_vector_type(8))) short bf16x8;
typedef __attribute__((ext_vector_type(4))) short bf16x4;
typedef __attribute__((ext_vector_type(4))) float f32x4;

struct __align__(16) TapEntry {
  int   i00, i01, i10, i11;    // BYTE offsets into xt's per-image slice
  float w00, w01, w10, w11;
};

static __device__ __forceinline__ ushort f2bf(float v) {
  unsigned u = __float_as_uint(v);
  unsigned rnd = 0x7fffu + ((u >> 16) & 1u);
  return (ushort)((u + rnd) >> 16);
}
static __device__ __forceinline__ float bf2f(short s) {
  return __uint_as_float(((unsigned)(unsigned short)s) << 16);
}

// ---- prep: x NCHW f32 -> xt NHWC bf16  +  weight repack to wbt ----
// wbt element (s, c16, lane=q*16+r, j) = w[co=c16*16+r][ci=(s&3)*32+q*8+j][tap=s>>2]
__global__ __launch_bounds__(256) void prep(const float* __restrict__ x,
                                            const float* __restrict__ w,
                                            ushort* __restrict__ xt,
                                            ushort* __restrict__ wbt) {
  const int blk = blockIdx.x;
  const int tid = threadIdx.x;
  if (blk < NB * HH) {
    const int b = blk >> 6, y = blk & 63;
    const int px = tid & 63, c8 = tid >> 6;
    const float* src = x + (size_t)b * CIN * HH * WW + y * WW + px;
    ushort* dst = xt + (((size_t)(b * HH + y) * WW) + px) * CIN;
    #pragma unroll
    for (int cc = 0; cc < 4; ++cc) {
      const int c0 = cc * 32 + c8 * 8;
      bf16x8 v;
      #pragma unroll
      for (int j = 0; j < 8; ++j)
        v[j] = (short)f2bf(src[(size_t)(c0 + j) * (HH * WW)]);
      *reinterpret_cast<bf16x8*>(dst + c0) = v;
    }
  } else {
    const int h = (blk - NB * HH) * 256 + tid;
    const int s   = h >> 10;
    const int c16 = (h >> 6) & 15;
    const int l   = h & 63;
    const int q   = l >> 4;
    const int r   = l & 15;
    const int co  = c16 * 16 + r;
    const int tap = s >> 2;
    const int ci0 = (s & 3) * 32 + q * 8;
    bf16x8 o;
    #pragma unroll
    for (int j = 0; j < 8; ++j)
      o[j] = (short)f2bf(w[(size_t)(co * CIN + ci0 + j) * NTAP + tap]);
    *reinterpret_cast<bf16x8*>(wbt + (size_t)h * 8) = o;
  }
}

// ---- main: px-split (32 px/block), coalesced gather, implicit GEMM ----
__global__ __launch_bounds__(256, 4)
void dcn8(const ushort* __restrict__ xt, const float* __restrict__ off,
          const ushort* __restrict__ wbt, float* __restrict__ out)
{
  __shared__ TapEntry taps[NTAP * PXB];                // 9216 B
  __shared__ __align__(16) char colsB[PXB * CROW];     // 8704 B

  const int tid = threadIdx.x;
  // b in low 3 bits: all 128 blocks of one image land on one XCD (L2 locality)
  const int b  = blockIdx.x & 7;
  const int ho = (blockIdx.x >> 3) & 63;
  const int ph = blockIdx.x >> 9;          // pixel half: wo in [ph*32, ph*32+32)

  for (int e = tid; e < NTAP * PXB; e += 256) {
    const int k  = e >> 5;
    const int lw = e & 31;
    const int wo = ph * PXB + lw;
    const float* op = off + (((size_t)(b * 18 + 2 * k) * HO + ho) * WO + wo);
    const float dy = op[0];
    const float dx = op[HO * WO];
    const float py  = (float)(ho - 1 + (k / 3)) + dy;
    const float pxf = (float)(wo - 1 + (k % 3)) + dx;
    const float y0f = floorf(py), x0f = floorf(pxf);
    const float fy = py - y0f, fx = pxf - x0f;
    const int y0 = (int)y0f, x0 = (int)x0f;
    const int y1 = y0 + 1,  x1 = x0 + 1;
    const bool vy0 = (unsigned)y0 < HH, vy1 = (unsigned)y1 < HH;
    const bool vx0 = (unsigned)x0 < WW, vx1 = (unsigned)x1 < WW;
    const int cy0 = min(max(y0, 0), HH - 1), cy1 = min(max(y1, 0), HH - 1);
    const int cx0 = min(max(x0, 0), WW - 1), cx1 = min(max(x1, 0), WW - 1);
    TapEntry t;
    t.i00 = (cy0 * WW + cx0) << 8;  t.i01 = (cy0 * WW + cx1) << 8;  // *CIN*2B
    t.i10 = (cy1 * WW + cx0) << 8;  t.i11 = (cy1 * WW + cx1) << 8;
    const float gy = 1.f - fy, gx = 1.f - fx;
    t.w00 = (vy0 && vx0) ? gy * gx : 0.f;
    t.w01 = (vy0 && vx1) ? gy * fx : 0.f;
    t.w10 = (vy1 && vx0) ? fy * gx : 0.f;
    t.w11 = (vy1 && vx1) ? fy * fx : 0.f;
    taps[e] = t;
  }

  const int lane = tid & 63;
  const int grp  = tid >> 6;   // wave id: px-group (producer) AND co-group (consumer)
  const int l15  = lane & 15;
  const int q    = lane >> 4;
  const int s16b = l15 * 16;   // gather: byte offset of 16B chunk in 256B row

  f32x4 acc[4][2];
  #pragma unroll
  for (int m = 0; m < 4; ++m)
    #pragma unroll
    for (int n = 0; n < 2; ++n)
      acc[m][n] = 0.f;

  const char* xb = reinterpret_cast<const char*>(xt)
                 + (size_t)b * (HH * WW * CIN * 2) + s16b;

  __syncthreads();   // taps ready

  #pragma unroll 1
  for (int tap = 0; tap < NTAP; ++tap) {
    // ---- gather: 2 pixels x 4 corners, all 8 loads in one flight ----
    // lanes 0-15 of each 16-lane group read one pixel-corner's contiguous 256B
    const int px0 = (grp << 3) + q;        // pq = 0
    const int px1 = (grp << 3) + 4 + q;    // pq = 1
    const TapEntry te0 = taps[tap * PXB + px0];
    const TapEntry te1 = taps[tap * PXB + px1];
    const bf16x8 a00 = *reinterpret_cast<const bf16x8*>(xb + te0.i00);
    const bf16x8 a01 = *reinterpret_cast<const bf16x8*>(xb + te0.i01);
    const bf16x8 a10 = *reinterpret_cast<const bf16x8*>(xb + te0.i10);
    const bf16x8 a11 = *reinterpret_cast<const bf16x8*>(xb + te0.i11);
    const bf16x8 b00 = *reinterpret_cast<const bf16x8*>(xb + te1.i00);
    const bf16x8 b01 = *reinterpret_cast<const bf16x8*>(xb + te1.i01);
    const bf16x8 b10 = *reinterpret_cast<const bf16x8*>(xb + te1.i10);
    const bf16x8 b11 = *reinterpret_cast<const bf16x8*>(xb + te1.i11);
    bf16x8 h0, h1;
    #pragma unroll
    for (int j = 0; j < 8; ++j) {
      const float v0 = te0.w00 * bf2f(a00[j]) + te0.w01 * bf2f(a01[j])
                     + te0.w10 * bf2f(a10[j]) + te0.w11 * bf2f(a11[j]);
      h0[j] = (short)f2bf(v0);
      const float v1 = te1.w00 * bf2f(b00[j]) + te1.w01 * bf2f(b01[j])
                     + te1.w10 * bf2f(b10[j]) + te1.w11 * bf2f(b11[j]);
      h1[j] = (short)f2bf(v1);
    }

    __syncthreads();   // previous tap's consumers done with colsB

    *reinterpret_cast<bf16x8*>(colsB + px0 * CROW + s16b) = h0;
    *reinterpret_cast<bf16x8*>(colsB + px1 * CROW + s16b) = h1;

    __syncthreads();   // colsB ready

    // ---- 4 barrier-free K-steps: A direct from wbt (1KB/wave contiguous) ----
    #pragma unroll
    for (int kk = 0; kk < 4; ++kk) {
      const int s = tap * 4 + kk;
      bf16x8 a[4], bb[2];
      #pragma unroll
      for (int m = 0; m < 4; ++m)
        a[m] = *reinterpret_cast<const bf16x8*>(
            wbt + ((size_t)((s * 16 + grp * 4 + m) * 64 + lane)) * 8);
      #pragma unroll
      for (int n = 0; n < 2; ++n)
        bb[n] = *reinterpret_cast<const bf16x8*>(
            colsB + (n * 16 + l15) * CROW + kk * 64 + q * 16);
      #pragma unroll
      for (int m = 0; m < 4; ++m)
        #pragma unroll
        for (int n = 0; n < 2; ++n)
          acc[m][n] = __builtin_amdgcn_mfma_f32_16x16x32_bf16(
              a[m], bb[n], acc[m][n], 0, 0, 0);
    }
  }

  // ---- epilogue: D row(co) = q*4+r (+m*16), col(wo) = ph*32 + n*16 + l15 ----
  #pragma unroll
  for (int m = 0; m < 4; ++m)
    #pragma unroll
    for (int n = 0; n < 2; ++n)
      #pragma unroll
      for (int r = 0; r < 4; ++r) {
        const int co = grp * 64 + m * 16 + q * 4 + r;
        const int wo = ph * PXB + n * 16 + l15;
        out[(((size_t)b * COUT + co) * HO + ho) * WO + wo] = acc[m][n][r];
      }
}

// ---- fallback (ws too small): round-1 f32-gather path ----
__global__ __launch_bounds__(256, 2)
void dcn_f32(const float* __restrict__ x, const float* __restrict__ off,
             const float* __restrict__ wgt, float* __restrict__ out)
{
  __shared__ TapEntry taps[NTAP * WO];
  __shared__ __align__(16) ushort colsf[WO * 40];
  const int tid = threadIdx.x;
  const int b  = blockIdx.x & 7;
  const int ho = blockIdx.x >> 3;
  for (int e = tid; e < NTAP * WO; e += 256) {
    const int k  = e >> 6;
    const int wo = e & 63;
    const float* op = off + (((size_t)(b * 18 + 2 * k) * HO + ho) * WO + wo);
    const float dy = op[0];
    const float dx = op[HO * WO];
    const float py  = (float)(ho - 1 + (k / 3)) + dy;
    const float pxf = (float)(wo - 1 + (k % 3)) + dx;
    const float y0f = floorf(py), x0f = floorf(pxf);
    const float fy = py - y0f, fx = pxf - x0f;
    const int y0 = (int)y0f, x0 = (int)x0f;
    const int y1 = y0 + 1,  x1 = x0 + 1;
    const bool vy0 = (unsigned)y0 < HH, vy1 = (unsigned)y1 < HH;
    const bool vx0 = (unsigned)x0 < WW, vx1 = (unsigned)x1 < WW;
    const int cy0 = min(max(y0, 0), HH - 1), cy1 = min(max(y1, 0), HH - 1);
    const int cx0 = min(max(x0, 0), WW - 1), cx1 = min(max(x1, 0), WW - 1);
    TapEntry t;
    t.i00 = cy0 * WW + cx0; t.i01 = cy0 * WW + cx1;
    t.i10 = cy1 * WW + cx0; t.i11 = cy1 * WW + cx1;
    const float gy = 1.f - fy, gx = 1.f - fx;
    t.w00 = (vy0 && vx0) ? gy * gx : 0.f;
    t.w01 = (vy0 && vx1) ? gy * fx : 0.f;
    t.w10 = (vy1 && vx0) ? fy * gx : 0.f;
    t.w11 = (vy1 && vx1) ? fy * fx : 0.f;
    taps[e] = t;
  }
  const int px = tid & 63, grp = tid >> 6, lane = tid & 63;
  const int l15 = lane & 15, q = lane >> 4;
  f32x4 acc[4][4];
  #pragma unroll
  for (int m = 0; m < 4; ++m)
    #pragma unroll
    for (int n = 0; n < 4; ++n) acc[m][n] = 0.f;
  const float* xb = x + (size_t)b * CIN * HH * WW;
  __syncthreads();
  for (int tap = 0; tap < NTAP; ++tap) {
    const TapEntry e = taps[tap * WO + px];
    for (int cb = 0; cb < 4; ++cb) {
      __syncthreads();
      {
        const float* xp = xb + (size_t)(cb * 32 + grp * 8) * (HH * WW);
        bf16x8 hv;
        #pragma unroll
        for (int j = 0; j < 8; ++j) {
          const float* p = xp + j * (HH * WW);
          const float v = e.w00 * p[e.i00] + e.w01 * p[e.i01]
                        + e.w10 * p[e.i10] + e.w11 * p[e.i11];
          hv[j] = (short)f2bf(v);
        }
        *reinterpret_cast<bf16x8*>(
            reinterpret_cast<char*>(colsf) + px * 80 + grp * 16) = hv;
      }
      __syncthreads();
      bf16x8 a[4], bbf[4];
      #pragma unroll
      for (int m = 0; m < 4; ++m) {
        const int co = grp * 64 + m * 16 + l15;
        bf16x8 t;
        #pragma unroll
        for (int j = 0; j < 8; ++j)
          t[j] = (short)f2bf(wgt[(size_t)(co * CIN + cb * 32 + q * 8 + j) * NTAP + tap]);
        a[m] = t;
      }
      #pragma unroll
      for (int n = 0; n < 4; ++n)
        bbf[n] = *reinterpret_cast<const bf16x8*>(
            reinterpret_cast<const char*>(colsf) + (n * 16 + l15) * 80 + q * 16);
      #pragma unroll
      for (int m = 0; m < 4; ++m)
        #pragma unroll
        for (int n = 0; n < 4; ++n)
          acc[m][n] = __builtin_amdgcn_mfma_f32_16x16x32_bf16(
              a[m], bbf[n], acc[m][n], 0, 0, 0);
    }
  }
  const int wco = grp * 64;
  #pragma unroll
  for (int m = 0; m < 4; ++m)
    #pragma unroll
    for (int n = 0; n < 4; ++n)
      #pragma unroll
      for (int r = 0; r < 4; ++r) {
        const int co = wco + m * 16 + q * 4 + r;
        const int wo = n * 16 + l15;
        out[(((size_t)b * COUT + co) * HO + ho) * WO + wo] = acc[m][n][r];
      }
}

extern "C" void kernel_launch(void* const* d_in, const int* in_sizes, int n_in,
                              void* d_out, int out_size, void* d_ws, size_t ws_size,
                              hipStream_t stream) {
  const float* x   = (const float*)d_in[0];   // [8,128,64,64]
  const float* off = (const float*)d_in[1];   // [8,18,64,64]
  const float* wgt = (const float*)d_in[2];   // [256,128,3,3]
  float* out = (float*)d_out;                 // [8,256,64,64]

  const size_t xt_bytes = (size_t)NB * HH * WW * CIN * sizeof(ushort);   // 8 MiB
  const size_t wb_bytes = (size_t)NSTEP * COUT * BK * sizeof(ushort);    // 576 KiB
  if (ws_size >= xt_bytes + wb_bytes) {
    ushort* xtp  = (ushort*)d_ws;
    ushort* wbtp = (ushort*)((char*)d_ws + xt_bytes);
    const int wchunks = NSTEP * COUT * BK / 8;        // 36864 16B chunks
    const int wblocks = wchunks / 256;                // 144
    prep<<<NB * HH + wblocks, 256, 0, stream>>>(x, wgt, xtp, wbtp);
    dcn8<<<NB * HO * 2, 256, 0, stream>>>(xtp, off, wbtp, out);
  } else {
    dcn_f32<<<NB * HO, 256, 0, stream>>>(x, off, wgt, out);
  }
}